// Round 6
// baseline (1181.813 us; speedup 1.0000x reference)
//
#include <hip/hip_runtime.h>

#define TAU_MAX  524287     // chunk sig[16t .. 16t+15] valid iff 0 <= t <= TAU_MAX
#define T_OUT    524287
#define RING     1152       // ring slots; 1 unit (16B) per slot -> 18 KiB LDS
#define R        4          // outputs per thread
#define NTHR     256
#define TB       (NTHR*R)   // 1024 outputs per block

// ---- LDS: one 16-B unit per slot. XOR-rotate placement (measured-good family):
// word(U) = (U>>3)*32 + (((U&7) + (U>>3)) & 7)*4  — bijective rotation per 8-slot row.
// Reads: lane slot-stride 4 -> cols {c0, c0+4, c0+1, c0+5, ...} all 8 distinct per
// 8 lanes. Writes: slot-stride 1 -> cols 0..7 distinct. (R4-family measured +4cyc.)
__device__ __forceinline__ int xw(int U) {
    const int row = U >> 3;
    return (row << 5) + ((((U & 7) + row) & 7) << 2);
}

__device__ __forceinline__ int slot_of(int tau) {
    return (int)(((unsigned)(tau + 4 * RING)) % (unsigned)RING);
}

// round-to-nearest-even f32 -> bf16
__device__ __forceinline__ unsigned f2bf(float f) {
    unsigned u = __float_as_uint(f);
    u += 0x7fffu + ((u >> 16) & 1u);
    return u >> 16;
}
__device__ __forceinline__ unsigned pack2(float re, float im) {
    return f2bf(re) | (f2bf(im) << 16);
}

// Load+pack unit G of chunk tau: elements 4G..4G+3 as (re,im) bf16 pairs.
template<int G>
__device__ __forceinline__ uint4 load_unit(const float* __restrict__ sre,
                                           const float* __restrict__ sim, int tau)
{
    uint4 u = make_uint4(0u, 0u, 0u, 0u);
    if ((unsigned)tau <= (unsigned)TAU_MAX) {
        const float4 a = *reinterpret_cast<const float4*>(sre + 16 * tau + 4 * G);
        const float4 b = *reinterpret_cast<const float4*>(sim + 16 * tau + 4 * G);
        u.x = pack2(a.x, b.x); u.y = pack2(a.y, b.y);
        u.z = pack2(a.z, b.z); u.w = pack2(a.w, b.w);
    }
    return u;
}

// Branch index for sweep G, element m: unit G holds elems e=4G+m; branch i=(16-e)&15.
__host__ __device__ constexpr int BR(int G, int m) {
    return (G == 0 && m == 0) ? 0 : 16 - 4 * G - m;
}

// One step of sweep G: thread chunk tau = t0+515-d at ring slot sl.
// Branch i>=1: cf = coeff[16*row + i], guard row in [0,1023].
// Branch 0 (G=0,m=0): cf = coeff[16*row + 16], guard row in [-1,1022].
// GK: 0 = none, 1 = low guard (head), 2 = high guard (tail).
template<int G, int GK>
__device__ __forceinline__ void step(int d, int sl,
                                     const float* __restrict__ coeff,
                                     const unsigned* __restrict__ lds,
                                     float (&are)[4][R], float (&aim)[4][R])
{
    const uint4 u = *reinterpret_cast<const uint4*>(&lds[xw(sl)]);
    const unsigned w[4] = {u.x, u.y, u.z, u.w};
    float cre[4], cim[4];
    #pragma unroll
    for (int m = 0; m < 4; ++m) {
        cre[m] = __uint_as_float(w[m] << 16);
        cim[m] = __uint_as_float(w[m] & 0xffff0000u);
    }
    #pragma unroll
    for (int r = 0; r < R; ++r) {
        const int row = d - 4 + r;
        #pragma unroll
        for (int m = 0; m < 4; ++m) {
            const bool isB0 = (G == 0 && m == 0);
            const bool ok = (GK == 0) ||
                            (GK == 1 ? (row >= (isB0 ? -1 : 0))
                                     : (row <= (isB0 ? 1022 : 1023)));
            if (ok) {
                const int co = isB0 ? 16 : (16 - 4 * G - m);
                const float cf = coeff[16 * row + co];   // wave-uniform -> s_load
                are[m][r] = fmaf(cf, cre[m], are[m][r]);
                aim[m][r] = fmaf(cf, cim[m], aim[m][r]);
            }
        }
    }
}

__device__ __forceinline__ void dec_slot(int& sl) {
    if (--sl < 0) sl += RING;
}

// twiddle tables: cos/sin(2*pi*k/16)
#define C1 0.9238795325112867f
#define C2 0.7071067811865476f
#define C3 0.3826834323650898f
__device__ __constant__ const float COS16[16] = { 1.f,  C1,  C2,  C3, 0.f, -C3, -C2, -C1,
                                                 -1.f, -C1, -C2, -C3, 0.f,  C3,  C2,  C1};
__device__ __constant__ const float SIN16[16] = { 0.f,  C3,  C2,  C1, 1.f,  C1,  C2,  C3,
                                                  0.f, -C3, -C2, -C1,-1.f, -C1, -C2, -C3};

template<int G>
__device__ __forceinline__ void sweep(int T0, int tid,
                                      const float* __restrict__ sre,
                                      const float* __restrict__ sim,
                                      const float* __restrict__ coeff,
                                      unsigned* __restrict__ lds,
                                      float (&o)[16][R])
{
    __syncthreads();   // previous sweep's tail reads must complete before restage

    // prologue: stage slots for tau in [T0+452, T0+1539] (1088 units)
    #pragma unroll 1
    for (int j = 0; j < 5; ++j) {
        const int u = tid + NTHR * j;
        if (u < 1088) {
            const int tau = T0 + 452 + u;
            *reinterpret_cast<uint4*>(&lds[xw(slot_of(tau))]) = load_unit<G>(sre, sim, tau);
        }
    }
    __syncthreads();

    float are[4][R], aim[4][R];
    #pragma unroll
    for (int m = 0; m < 4; ++m)
        #pragma unroll
        for (int r = 0; r < R; ++r) { are[m][r] = 0.f; aim[m][r] = 0.f; }

    const int t0 = T0 + tid * R;
    int sl = slot_of(t0 + 515);

    // head: d in [0,4), low-guarded
    #pragma unroll 1
    for (int d = 0; d < 4; ++d) { step<G, 1>(d, sl, coeff, lds, are, aim); dec_slot(sl); }

    // 16 tiles of 64 deltas; T14 split: issue tile-(k+1) loads early, write late.
    #pragma unroll 1
    for (int k = 0; k < 16; ++k) {
        uint4 sv;
        int swd = 0;
        const bool st = (tid < 64);
        if (st) {
            const int stau = T0 + 388 - 64 * k + tid;
            sv  = load_unit<G>(sre, sim, stau);
            swd = xw(slot_of(stau));
        }
        const int d0 = (k == 0) ? 4 : 64 * k;
        const int d1 = 64 * (k + 1);
        #pragma unroll 4
        for (int d = d0; d < d1; ++d) { step<G, 0>(d, sl, coeff, lds, are, aim); dec_slot(sl); }
        if (st) *reinterpret_cast<uint4*>(&lds[swd]) = sv;
        __syncthreads();
    }

    // tail: d in [1024,1028), high-guarded
    #pragma unroll 1
    for (int d = 1024; d < 1028; ++d) { step<G, 2>(d, sl, coeff, lds, are, aim); dec_slot(sl); }

    // fold this sweep's 4 branches into the real-part DFT accumulators.
    // o[c][r] += cos(2pi*i*c/16)*are - sin(2pi*i*c/16)*aim, i = BR(G,m).
    #pragma unroll
    for (int c = 0; c < 16; ++c) {
        #pragma unroll
        for (int m = 0; m < 4; ++m) {
            const int k = (BR(G, m) * c) & 15;   // compile-time after unroll
            const float wc = COS16[k], ws = SIN16[k];
            #pragma unroll
            for (int r = 0; r < R; ++r)
                o[c][r] = fmaf(wc, are[m][r], fmaf(-ws, aim[m][r], o[c][r]));
        }
    }
}

__global__ __launch_bounds__(NTHR, 3)
void wdm_kernel(const float* __restrict__ sre,
                const float* __restrict__ sim,
                const float* __restrict__ coeff,
                float* __restrict__ out)
{
    extern __shared__ unsigned lds[];
    const int tid = threadIdx.x;
    const int T0  = blockIdx.x * TB;

    float o[16][R];
    #pragma unroll
    for (int c = 0; c < 16; ++c)
        #pragma unroll
        for (int r = 0; r < R; ++r) o[c][r] = 0.f;

    sweep<3>(T0, tid, sre, sim, coeff, lds, o);
    sweep<2>(T0, tid, sre, sim, coeff, lds, o);
    sweep<1>(T0, tid, sre, sim, coeff, lds, o);
    sweep<0>(T0, tid, sre, sim, coeff, lds, o);

    const int t0 = T0 + tid * R;
    #pragma unroll
    for (int c = 0; c < 16; ++c) {
        float* orow = out + (long)c * T_OUT;
        #pragma unroll
        for (int r = 0; r < R; ++r) {
            const int t = t0 + r;
            if (t < T_OUT) orow[t] = o[c][r];
        }
    }
}

extern "C" void kernel_launch(void* const* d_in, const int* in_sizes, int n_in,
                              void* d_out, int out_size, void* d_ws, size_t ws_size,
                              hipStream_t stream)
{
    const float* sre   = (const float*)d_in[0];
    const float* sim   = (const float*)d_in[1];
    const float* coeff = (const float*)d_in[2];
    float* out = (float*)d_out;

    // 512 blocks x 1024 outputs = 524288 >= 524287; LDS = 1152 units * 16 B = 18432 B.
    wdm_kernel<<<dim3(512), dim3(NTHR), RING * 16, stream>>>(sre, sim, coeff, out);
}

// Round 7
// 407.443 us; speedup vs baseline: 2.9006x; 2.9006x over previous
//
#include <hip/hip_runtime.h>

#define TAU_MAX  524287     // chunk sig[16t .. 16t+15] valid iff 0 <= t <= TAU_MAX
#define T_OUT    524287
#define RINGR    576        // ring capacity in RECORDS (record = 2 chunks = 128 B) -> 72 KiB
#define R        4          // outputs per thread
#define NTHR     256
#define TB       (NTHR*R)   // 1024 outputs per block
#define PROWS    1022       // packed coeff-pair rows (main loop uses rows 0..1021)

typedef _Float16 h2 __attribute__((ext_vector_type(2)));

__device__ __forceinline__ unsigned packh2(float a, float b) {
    h2 v; v.x = (_Float16)a; v.y = (_Float16)b;
    return __builtin_bit_cast(unsigned, v);
}
__device__ __forceinline__ h2 as_h2(unsigned u) { return __builtin_bit_cast(h2, u); }

// ---- prep: P[16*row+co'] = (h[16row+CO], h[16row+16+CO]) as f16x2, CO = co'?co':16.
// Pair = taps (row, row+1) of branch co' (co'=0 is branch 0, which uses offset 16).
__global__ void prep_kernel(const float* __restrict__ coeff, unsigned* __restrict__ P)
{
    const int e = blockIdx.x * 256 + threadIdx.x;
    if (e < PROWS * 16) {
        const int row = e >> 4, cop = e & 15;
        const int CO = cop ? cop : 16;
        P[e] = packh2(coeff[16 * row + CO], coeff[16 * row + 16 + CO]);
    }
}

// ---- LDS: record s = chunks (2s, 2s+1), 32 words: unit q(0..7) = 4 words.
// q<4: re-pairs elems 4q..4q+3; q>=4: im-pairs. Pair = (f16 x[2s+1][j], f16 x[2s][j]).
// Swizzle: unit q of slot sl at word 32*sl + ((q + ((sl>>1)&7))&7)*4.
// Reads: lane record-stride 2 -> rot stride 1 -> 8 distinct cols per 8 lanes (1-way).
// Writes: stride-1 units, fixed s per 8 lanes -> q covers all cols (1-way).
__device__ __forceinline__ int slot_of(int s) {
    return (int)(((unsigned)(s + 4 * RINGR)) % (unsigned)RINGR);
}
__device__ __forceinline__ int unit_word(int sl, int q) {
    return (sl << 5) + (((q + ((sl >> 1) & 7)) & 7) << 2);
}

// Build one staged unit of record s (guards each chunk; OOB -> 0).
__device__ __forceinline__ uint4 make_unit(const float* __restrict__ sre,
                                           const float* __restrict__ sim,
                                           int s, int q)
{
    const float* src = (q >> 2) ? sim : sre;
    const int jb = (q & 3) << 2;
    const int to = 2 * s + 1, te = 2 * s;
    float4 vo = make_float4(0.f, 0.f, 0.f, 0.f), ve = make_float4(0.f, 0.f, 0.f, 0.f);
    if ((unsigned)to <= (unsigned)TAU_MAX) vo = *reinterpret_cast<const float4*>(src + 16 * to + jb);
    if ((unsigned)te <= (unsigned)TAU_MAX) ve = *reinterpret_cast<const float4*>(src + 16 * te + jb);
    uint4 u;
    u.x = packh2(vo.x, ve.x); u.y = packh2(vo.y, ve.y);
    u.z = packh2(vo.z, ve.z); u.w = packh2(vo.w, ve.w);
    return u;
}

// ---- main step-pair: taps d and d+1 (d even), record s=(t0+514-d)/2 at slot sl.
// Element j feeds acc[j] (branch (16-j)&15); coeff pair cfb[16r + ((16-j)&15)].
__device__ __forceinline__ void step_pair(int d, int sl,
                                          const unsigned* __restrict__ P,
                                          const unsigned* __restrict__ lds,
                                          float (&are)[16][R], float (&aim)[16][R])
{
    uint4 ru[8];
    const int base = sl << 5;
    const int rot  = (sl >> 1) & 7;
    #pragma unroll
    for (int q = 0; q < 8; ++q)
        ru[q] = *reinterpret_cast<const uint4*>(&lds[base + (((q + rot) & 7) << 2)]);
    const unsigned* cfb = P + 16 * (d - 4);   // uniform, 64 contiguous dwords
    #pragma unroll
    for (int r = 0; r < R; ++r) {
        #pragma unroll
        for (int j = 0; j < 16; ++j) {
            const h2 cp = as_h2(cfb[16 * r + ((16 - j) & 15)]);
            const uint4 uR = ru[j >> 2];
            const uint4 uI = ru[4 + (j >> 2)];
            const int m = j & 3;
            const unsigned wr_ = (m == 0) ? uR.x : (m == 1) ? uR.y : (m == 2) ? uR.z : uR.w;
            const unsigned wi_ = (m == 0) ? uI.x : (m == 1) ? uI.y : (m == 2) ? uI.z : uI.w;
            are[j][r] = __builtin_amdgcn_fdot2(cp, as_h2(wr_), are[j][r], false);
            aim[j][r] = __builtin_amdgcn_fdot2(cp, as_h2(wi_), aim[j][r], false);
        }
    }
}

// ---- edge scalar steps: exact f32, straight from global (no LDS dependence).
__device__ __forceinline__ void load_chunk_f32(const float* __restrict__ sre,
                                               const float* __restrict__ sim,
                                               int tau, float (&cre)[16], float (&cim)[16])
{
    if ((unsigned)tau <= (unsigned)TAU_MAX) {
        #pragma unroll
        for (int qq = 0; qq < 4; ++qq) {
            const float4 a = *reinterpret_cast<const float4*>(sre + 16 * tau + 4 * qq);
            const float4 b = *reinterpret_cast<const float4*>(sim + 16 * tau + 4 * qq);
            cre[4*qq+0] = a.x; cre[4*qq+1] = a.y; cre[4*qq+2] = a.z; cre[4*qq+3] = a.w;
            cim[4*qq+0] = b.x; cim[4*qq+1] = b.y; cim[4*qq+2] = b.z; cim[4*qq+3] = b.w;
        }
    } else {
        #pragma unroll
        for (int j = 0; j < 16; ++j) { cre[j] = 0.f; cim[j] = 0.f; }
    }
}

template<int GK>   // 1 = head (low guard), 2 = tail (high guard)
__device__ __forceinline__ void step_scalar(int d, int t0,
                                            const float* __restrict__ sre,
                                            const float* __restrict__ sim,
                                            const float* __restrict__ coeff,
                                            float (&are)[16][R], float (&aim)[16][R])
{
    float cre[16], cim[16];
    load_chunk_f32(sre, sim, t0 + 515 - d, cre, cim);
    #pragma unroll
    for (int r = 0; r < R; ++r) {
        const int row = d - 4 + r;
        if (GK == 1 ? (row >= 0) : (row <= 1023)) {
            #pragma unroll
            for (int j = 1; j < 16; ++j) {
                const float cf = coeff[16 * row + 16 - j];
                are[j][r] = fmaf(cf, cre[j], are[j][r]);
                aim[j][r] = fmaf(cf, cim[j], aim[j][r]);
            }
        }
        if (GK == 1 ? (row >= -1) : (row <= 1022)) {
            const float cf = coeff[16 * row + 16];
            are[0][r] = fmaf(cf, cre[0], are[0][r]);
            aim[0][r] = fmaf(cf, cim[0], aim[0][r]);
        }
    }
}

// twiddle tables: cos/sin(2*pi*k/16), compile-time indexed in the fold
#define TC1 0.9238795325112867f
#define TC2 0.7071067811865476f
#define TC3 0.3826834323650898f
__device__ __constant__ const float COS16[16] = { 1.f,  TC1,  TC2,  TC3, 0.f, -TC3, -TC2, -TC1,
                                                 -1.f, -TC1, -TC2, -TC3, 0.f,  TC3,  TC2,  TC1};
__device__ __constant__ const float SIN16[16] = { 0.f,  TC3,  TC2,  TC1, 1.f,  TC1,  TC2,  TC3,
                                                  0.f, -TC3, -TC2, -TC1,-1.f, -TC1, -TC2, -TC3};

__global__ __launch_bounds__(NTHR, 2)
void wdm_kernel(const float* __restrict__ sre,
                const float* __restrict__ sim,
                const float* __restrict__ coeff,
                const unsigned* __restrict__ P,
                float* __restrict__ out)
{
    extern __shared__ unsigned lds[];
    const int tid = threadIdx.x;
    const int T0  = blockIdx.x * TB;
    const int t0  = T0 + tid * R;
    const int S0  = (T0 >> 1) + 226;          // prologue records [S0, S0+543]

    // prologue stage: 544 records = 4352 units, 17/thread
    #pragma unroll 1
    for (int jj = 0; jj < 17; ++jj) {
        const int u = tid + NTHR * jj;
        const int s = S0 + (u >> 3), q = u & 7;
        const uint4 v = make_unit(sre, sim, s, q);
        *reinterpret_cast<uint4*>(&lds[unit_word(slot_of(s), q)]) = v;
    }

    float are[16][R], aim[16][R];
    #pragma unroll
    for (int j = 0; j < 16; ++j)
        #pragma unroll
        for (int r = 0; r < R; ++r) { are[j][r] = 0.f; aim[j][r] = 0.f; }

    // head: d = 0..3, guarded, global f32
    #pragma unroll 1
    for (int d = 0; d < 4; ++d) step_scalar<1>(d, t0, sre, sim, coeff, are, aim);

    __syncthreads();

    int sl = slot_of((t0 >> 1) + 255);        // record for d=4

    // 16 tiles of 64 taps (32 step-pairs); T14 split: load early, ds_write late.
    #pragma unroll 1
    for (int k = 0; k < 16; ++k) {
        uint4 sv = make_uint4(0u, 0u, 0u, 0u);
        int swd = 0;
        const bool st = (k < 15);             // tile 15 stages nothing (tail is global)
        if (st) {
            const int s = (T0 >> 1) + 194 - 32 * k + (tid >> 3);
            sv  = make_unit(sre, sim, s, tid & 7);
            swd = unit_word(slot_of(s), tid & 7);
        }
        const int d0 = (k == 0) ? 4 : 64 * k;
        const int d1 = 64 * (k + 1);
        #pragma unroll 1
        for (int d = d0; d < d1; d += 2) {
            step_pair(d, sl, P, lds, are, aim);
            if (--sl < 0) sl += RINGR;
        }
        if (st) *reinterpret_cast<uint4*>(&lds[swd]) = sv;
        __syncthreads();
    }

    // tail: d = 1024..1027, guarded, global f32
    #pragma unroll 1
    for (int d = 1024; d < 1028; ++d) step_scalar<2>(d, t0, sre, sim, coeff, are, aim);

    // fold: real part of 16-point inverse DFT; branch i=(16-j)&15, compile-time twiddles
    float o[16][R];
    #pragma unroll
    for (int c = 0; c < 16; ++c)
        #pragma unroll
        for (int r = 0; r < R; ++r) o[c][r] = 0.f;
    #pragma unroll
    for (int c = 0; c < 16; ++c) {
        #pragma unroll
        for (int j = 0; j < 16; ++j) {
            const int i  = (16 - j) & 15;
            const int kk = (i * c) & 15;
            const float wc = COS16[kk], ws = SIN16[kk];
            #pragma unroll
            for (int r = 0; r < R; ++r)
                o[c][r] = fmaf(wc, are[j][r], fmaf(-ws, aim[j][r], o[c][r]));
        }
    }

    #pragma unroll
    for (int c = 0; c < 16; ++c) {
        float* orow = out + (long)c * T_OUT;
        #pragma unroll
        for (int r = 0; r < R; ++r) {
            const int t = t0 + r;
            if (t < T_OUT) orow[t] = o[c][r];
        }
    }
}

extern "C" void kernel_launch(void* const* d_in, const int* in_sizes, int n_in,
                              void* d_out, int out_size, void* d_ws, size_t ws_size,
                              hipStream_t stream)
{
    const float* sre   = (const float*)d_in[0];
    const float* sim   = (const float*)d_in[1];
    const float* coeff = (const float*)d_in[2];
    unsigned* P = (unsigned*)d_ws;            // 1022*16*4 = 65408 B packed coeff pairs
    float* out = (float*)d_out;

    prep_kernel<<<dim3((PROWS * 16 + 255) / 256), dim3(256), 0, stream>>>(coeff, P);
    // 512 blocks x 1024 outputs; LDS = 576 records * 128 B = 73728 B -> 2 blocks/CU.
    wdm_kernel<<<dim3(512), dim3(NTHR), RINGR * 128, stream>>>(sre, sim, coeff, P, out);
}

// Round 8
// 121.271 us; speedup vs baseline: 9.7452x; 3.3598x over previous
//
#include <hip/hip_runtime.h>

#define T_OUT    524287
#define SIG_LEN  8388608
#define SPITCH   525376            // f16 per plane: m in [-544, 524832) + pad
#define MOFF     544
#define NPLANES  32                // 16 phases x (re, im)
#define NSTEP    33                // k0 = -31 + 32u, u in [0,33)

typedef _Float16 f16;
typedef _Float16 f16x8 __attribute__((ext_vector_type(8)));
typedef float    f32x4 __attribute__((ext_vector_type(4)));

// ============ prep 1: phase-split signal to f16 planes ============
// S16[plane(i,e)][MOFF + m] = f16( sig_ext[16m - i] ), e=0 re, e=1 im.
// Block covers 256 consecutive m for all 32 planes (reads stay in a 32KB
// window -> L1-served; writes 64B contiguous per thread).
__global__ void prep_sig(const float* __restrict__ sre,
                         const float* __restrict__ sim,
                         f16* __restrict__ S16)
{
    const int tid = threadIdx.x;
    const int pl = tid >> 3, sub = tid & 7;
    const int i = pl >> 1, e = pl & 1;
    const float* src = e ? sim : sre;
    const int m0 = -544 + 256 * blockIdx.x + 32 * sub;
    if (m0 > 524800) return;
    f16 v[32];
    #pragma unroll
    for (int k = 0; k < 32; ++k) {
        const long n = 16L * (m0 + k) - i;
        v[k] = (f16)((n >= 0 && n < SIG_LEN) ? src[n] : 0.f);
    }
    f16* dst = S16 + (long)pl * SPITCH + (MOFF + m0);
    #pragma unroll
    for (int q = 0; q < 4; ++q)
        *reinterpret_cast<uint4*>(dst + 8 * q) = *reinterpret_cast<uint4*>(&v[8 * q]);
}

// ============ prep 2: exact per-lane A fragments (coeff Toeplitz) ============
// frag fi = i*33 + u; AF[(fi*64 + lane)*8 + e] = Hpad[k0 + p + 31 - (8g+e)],
// p = lane&15, g = lane>>4, k0 = 32u-31, Hpad[d] = coeff[16d+i] for d in [0,1024).
__global__ void prep_afrag(const float* __restrict__ coeff, f16* __restrict__ AF)
{
    const int gid = blockIdx.x * 256 + threadIdx.x;
    if (gid >= 16 * NSTEP * 64) return;
    const int lane = gid & 63;
    const int fi = gid >> 6;
    const int i = fi / NSTEP, u = fi % NSTEP;
    const int k0 = 32 * u - 31;
    const int p = lane & 15, g = lane >> 4;
    f16 v[8];
    #pragma unroll
    for (int e = 0; e < 8; ++e) {
        const int d = k0 + p + 31 - 8 * g - e;
        v[e] = (f16)((d >= 0 && d < 1024) ? coeff[16 * d + i] : 0.f);
    }
    *reinterpret_cast<f16x8*>(AF + (long)gid * 8) = *reinterpret_cast<f16x8*>(v);
}

// twiddles cos/sin(2*pi*k/16)
#define TC1 0.9238795325112867f
#define TC2 0.7071067811865476f
#define TC3 0.3826834323650898f
__device__ __constant__ const float COS16[16] = { 1.f,  TC1,  TC2,  TC3, 0.f, -TC3, -TC2, -TC1,
                                                 -1.f, -TC1, -TC2, -TC3, 0.f,  TC3,  TC2,  TC1};
__device__ __constant__ const float SIN16[16] = { 0.f,  TC3,  TC2,  TC1, 1.f,  TC1,  TC2,  TC3,
                                                  0.f, -TC3, -TC2, -TC1,-1.f, -TC1, -TC2, -TC3};

// ============ main: MFMA polyphase FIR + 16-pt real inverse DFT ============
// Block = 256-t tile. Ring: 32 planes x 512 f16 (32KB). Wave w owns branches
// 4w..4w+3. Step u: B-frag = ds_read_b128 at ((t0+512-32u+16n+8g)&511);
// A-frag = prefetched global dwordx4 (L2-resident, 540KB total).
__global__ __launch_bounds__(256, 3)
void wdm_mfma(const f16* __restrict__ S16, const f16* __restrict__ AF,
              float* __restrict__ out)
{
    extern __shared__ char lds_raw[];
    f16*   ring = reinterpret_cast<f16*>(lds_raw);    // [32][512] f16
    float* ulds = reinterpret_cast<float*>(lds_raw);  // [32][264] f32 (after)

    const int tid = threadIdx.x;
    const int tile = ((blockIdx.x & 7) << 8) + (blockIdx.x >> 3);  // XCD swizzle
    const int t0 = tile << 8;

    const int lane = tid & 63;
    const int w = tid >> 6;
    const int n16 = lane & 15, g4 = lane >> 4;
    const int boff = 16 * n16 + 8 * g4;

    // staging role: plane pl = tid>>3, 4 m's (8B) per thread per granule.
    // granule j covers m in [t0+752-32j, t0+783-32j], j in [0,41).
    const int pl = tid >> 3, sub = tid & 7;
    const f16* gsrc = S16 + (long)pl * SPITCH + MOFF;
    f16* ring_pl = ring + (pl << 9);

    #pragma unroll 1
    for (int j = 0; j <= 10; ++j) {                    // prologue: granules 0..10
        const int m0 = t0 + 752 - 32 * j + 4 * sub;
        const uint2 v = *reinterpret_cast<const uint2*>(gsrc + m0);
        *reinterpret_cast<uint2*>(ring_pl + (m0 & 511)) = v;
    }
    __syncthreads();

    f32x4 acc[4][2] = {};

    f16x8 a_cur[4];
    #pragma unroll
    for (int b = 0; b < 4; ++b)
        a_cur[b] = *reinterpret_cast<const f16x8*>(
            AF + ((long)((4 * w + b) * NSTEP + 0) * 64 + lane) * 8);

    #pragma unroll 1
    for (int u = 0; u < NSTEP; ++u) {
        // T14: issue next-granule global loads early
        uint2 sv; int m0s = 0;
        const bool dostage = (u <= 29);                // granule 11+u, last = 40
        if (dostage) {
            m0s = t0 + 400 - 32 * u + 4 * sub;
            sv = *reinterpret_cast<const uint2*>(gsrc + m0s);
        }
        // prefetch next A-frags (L2)
        f16x8 a_nxt[4];
        if (u < NSTEP - 1) {
            #pragma unroll
            for (int b = 0; b < 4; ++b)
                a_nxt[b] = *reinterpret_cast<const f16x8*>(
                    AF + ((long)((4 * w + b) * NSTEP + (u + 1)) * 64 + lane) * 8);
        }
        // B reads + MFMA
        const int mb = (t0 + 512 - 32 * u + boff) & 511;
        #pragma unroll
        for (int b = 0; b < 4; ++b) {
            const int i = 4 * w + b;
            const f16x8 bre = *reinterpret_cast<const f16x8*>(ring + ((2 * i + 0) << 9) + mb);
            const f16x8 bim = *reinterpret_cast<const f16x8*>(ring + ((2 * i + 1) << 9) + mb);
            acc[b][0] = __builtin_amdgcn_mfma_f32_16x16x32_f16(a_cur[b], bre, acc[b][0], 0, 0, 0);
            acc[b][1] = __builtin_amdgcn_mfma_f32_16x16x32_f16(a_cur[b], bim, acc[b][1], 0, 0, 0);
        }
        if (u < NSTEP - 1) {
            #pragma unroll
            for (int b = 0; b < 4; ++b) a_cur[b] = a_nxt[b];
        }
        if (dostage)
            *reinterpret_cast<uint2*>(ring_pl + (m0s & 511)) = sv;
        __syncthreads();
    }

    // ---- write u to LDS (ring no longer needed; last barrier protects it)
    #pragma unroll
    for (int b = 0; b < 4; ++b) {
        const int i = 4 * w + b;
        #pragma unroll
        for (int e = 0; e < 2; ++e)
            #pragma unroll
            for (int j = 0; j < 4; ++j)
                ulds[(2 * i + e) * 264 + (16 * n16 + 4 * g4 + j)] = acc[b][e][j];
    }
    __syncthreads();

    // ---- per-thread 16-pt inverse DFT (real part) + store
    float ur[16], ui[16];
    #pragma unroll
    for (int i = 0; i < 16; ++i) {
        ur[i] = ulds[(2 * i + 0) * 264 + tid];
        ui[i] = ulds[(2 * i + 1) * 264 + tid];
    }
    const int t = t0 + tid;
    #pragma unroll
    for (int c = 0; c < 16; ++c) {
        float o = 0.f;
        #pragma unroll
        for (int i = 0; i < 16; ++i) {
            const int k = (i * c) & 15;
            o = fmaf(COS16[k], ur[i], fmaf(-SIN16[k], ui[i], o));
        }
        if (t < T_OUT) out[(long)c * T_OUT + t] = o;
    }
}

extern "C" void kernel_launch(void* const* d_in, const int* in_sizes, int n_in,
                              void* d_out, int out_size, void* d_ws, size_t ws_size,
                              hipStream_t stream)
{
    const float* sre   = (const float*)d_in[0];
    const float* sim   = (const float*)d_in[1];
    const float* coeff = (const float*)d_in[2];
    float* out = (float*)d_out;

    f16* S16 = (f16*)d_ws;                         // 32 * 525376 * 2B = 33.62 MB
    f16* AF  = S16 + (long)NPLANES * SPITCH;       // 16*33*512 f16 = 540 KB

    // m-range [-544, 524800] in 256-m blocks -> 2053 blocks (guarded)
    prep_sig<<<dim3(2053), dim3(256), 0, stream>>>(sre, sim, S16);
    prep_afrag<<<dim3((16 * NSTEP * 64 + 255) / 256), dim3(256), 0, stream>>>(coeff, AF);
    // 2048 tiles x 256 t; LDS = max(ring 32768, ulds 33792) = 33792 B
    wdm_mfma<<<dim3(2048), dim3(256), 33792, stream>>>(S16, AF, out);
}

// Round 9
// 92.165 us; speedup vs baseline: 12.8228x; 1.3158x over previous
//
#include <hip/hip_runtime.h>

#define T_OUT    524287
#define SIG_LEN  8388608
#define SPITCH   525376            // f16 per plane: m in [-544, 524832) + pad
#define MOFF     544
#define NPLANES  32                // 16 phases x (re, im)
#define NSTEP    33                // k0 = -31 + 32u, u in [0,33)

typedef _Float16 f16;
typedef _Float16 f16x8 __attribute__((ext_vector_type(8)));
typedef float    f32x4 __attribute__((ext_vector_type(4)));

// ============ prep 1: phase-split signal to f16 planes ============
// S16[pl=2i+e][MOFF+m] = f16( src_e[16m - i] ).  Block = 256-m window.
// Phase 1: coalesced float4 loads of sig n-window [N0, N0+4096], convert f16,
// linear LDS. Phase 2: strided LDS gather (8 f16, stride 16) -> b128 store.
__global__ __launch_bounds__(256)
void prep_sig(const float* __restrict__ sre,
              const float* __restrict__ sim,
              f16* __restrict__ S16)
{
    __shared__ f16 lf[2 * 4104];
    const int tid = threadIdx.x;
    const int M0 = -544 + 256 * (int)blockIdx.x;
    const long N0 = 16L * M0 - 16;

    // phase 1: 8 float4 per thread (2 comps x 4 chunks)
    #pragma unroll
    for (int c = 0; c < 8; ++c) {
        const int e = c >> 2, cc = c & 3;
        const int k = 4 * (tid + 256 * cc);          // [0,4096) step 4
        const long n = N0 + k;
        const float* src = e ? sim : sre;
        float4 v = make_float4(0.f, 0.f, 0.f, 0.f);
        if (n >= 0 && n + 4 <= SIG_LEN) {
            v = *reinterpret_cast<const float4*>(src + n);
        } else {
            if (n     >= 0 && n     < SIG_LEN) v.x = src[n];
            if (n + 1 >= 0 && n + 1 < SIG_LEN) v.y = src[n + 1];
            if (n + 2 >= 0 && n + 2 < SIG_LEN) v.z = src[n + 2];
            if (n + 3 >= 0 && n + 3 < SIG_LEN) v.w = src[n + 3];
        }
        f16 h[4] = {(f16)v.x, (f16)v.y, (f16)v.z, (f16)v.w};
        *reinterpret_cast<uint2*>(&lf[e * 4104 + k]) = *reinterpret_cast<const uint2*>(h);
    }
    if (tid < 2) {                                   // the k=4096 straggler (i=0,j=7,a=31)
        const long n = N0 + 4096;
        const float x = (n >= 0 && n < SIG_LEN) ? (tid ? sim[n] : sre[n]) : 0.f;
        lf[tid * 4104 + 4096] = (f16)x;
    }
    __syncthreads();

    // phase 2: task (pl, a): plane pl, m-run [M0+8a, M0+8a+8)
    const int pl = tid & 31, i = pl >> 1, e = pl & 1;
    #pragma unroll
    for (int q = 0; q < 4; ++q) {
        const int a = (tid >> 5) + 8 * q;            // [0,32)
        const int mr = M0 + 8 * a;
        if (mr + 8 <= 524832) {                      // store fits plane extent
            f16 h[8];
            #pragma unroll
            for (int j = 0; j < 8; ++j)
                h[j] = lf[e * 4104 + 128 * a + 16 * j + 16 - i];
            *reinterpret_cast<uint4*>(S16 + (long)pl * SPITCH + (MOFF + mr)) =
                *reinterpret_cast<const uint4*>(h);
        }
    }
}

// ============ prep 2: exact per-lane A fragments (coeff Toeplitz) ============
// frag fi = i*33 + u; AF[(fi*64 + lane)*8 + e] = Hpad[k0 + p + 31 - (8g+e)],
// p = lane&15, g = lane>>4, k0 = 32u-31, Hpad[d] = coeff[16d+i] for d in [0,1024).
__global__ void prep_afrag(const float* __restrict__ coeff, f16* __restrict__ AF)
{
    const int gid = blockIdx.x * 256 + threadIdx.x;
    if (gid >= 16 * NSTEP * 64) return;
    const int lane = gid & 63;
    const int fi = gid >> 6;
    const int i = fi / NSTEP, u = fi % NSTEP;
    const int k0 = 32 * u - 31;
    const int p = lane & 15, g = lane >> 4;
    f16 v[8];
    #pragma unroll
    for (int e = 0; e < 8; ++e) {
        const int d = k0 + p + 31 - 8 * g - e;
        v[e] = (f16)((d >= 0 && d < 1024) ? coeff[16 * d + i] : 0.f);
    }
    *reinterpret_cast<f16x8*>(AF + (long)gid * 8) = *reinterpret_cast<const f16x8*>(v);
}

// twiddles cos/sin(2*pi*k/16)
#define TC1 0.9238795325112867f
#define TC2 0.7071067811865476f
#define TC3 0.3826834323650898f
__device__ __constant__ const float COS16[16] = { 1.f,  TC1,  TC2,  TC3, 0.f, -TC3, -TC2, -TC1,
                                                 -1.f, -TC1, -TC2, -TC3, 0.f,  TC3,  TC2,  TC1};
__device__ __constant__ const float SIN16[16] = { 0.f,  TC3,  TC2,  TC1, 1.f,  TC1,  TC2,  TC3,
                                                  0.f, -TC3, -TC2, -TC1,-1.f, -TC1, -TC2, -TC3};

// ============ main: MFMA polyphase FIR + 16-pt real inverse DFT ============
__device__ __forceinline__ void mstep(int u, int t0, int tid, int w, int lane, int boff,
                                      const f16* __restrict__ gsrc,
                                      f16* __restrict__ ring_pl,
                                      const f16* __restrict__ ring,
                                      const f16* __restrict__ AF,
                                      f16x8 (&cur)[4], f16x8 (&nxt)[4],
                                      f32x4 (&acc)[4][2], bool prefetch)
{
    // T14: issue next-granule staging loads early
    uint2 sv; int m0s = 0;
    const bool dostage = (u <= 29);                  // granule 11+u, last = 40
    if (dostage) {
        m0s = t0 + 400 - 32 * u + 4 * (tid & 7);
        sv = *reinterpret_cast<const uint2*>(gsrc + m0s);
    }
    // prefetch next A-frags (L2-resident, 540KB)
    if (prefetch) {
        #pragma unroll
        for (int b = 0; b < 4; ++b)
            nxt[b] = *reinterpret_cast<const f16x8*>(
                AF + ((long)((4 * w + b) * NSTEP + (u + 1)) * 64 + lane) * 8);
    }
    // B reads + MFMA
    const int mb = (t0 + 512 - 32 * u + boff) & 511;
    #pragma unroll
    for (int b = 0; b < 4; ++b) {
        const int i = 4 * w + b;
        const f16x8 bre = *reinterpret_cast<const f16x8*>(ring + ((2 * i + 0) << 9) + mb);
        const f16x8 bim = *reinterpret_cast<const f16x8*>(ring + ((2 * i + 1) << 9) + mb);
        acc[b][0] = __builtin_amdgcn_mfma_f32_16x16x32_f16(cur[b], bre, acc[b][0], 0, 0, 0);
        acc[b][1] = __builtin_amdgcn_mfma_f32_16x16x32_f16(cur[b], bim, acc[b][1], 0, 0, 0);
    }
    if (dostage)
        *reinterpret_cast<uint2*>(ring_pl + (m0s & 511)) = sv;
    __syncthreads();
}

__global__ __launch_bounds__(256, 5)
void wdm_mfma(const f16* __restrict__ S16, const f16* __restrict__ AF,
              float* __restrict__ out)
{
    extern __shared__ char lds_raw[];
    f16*   ring = reinterpret_cast<f16*>(lds_raw);    // [32][512] f16 = 32KB
    float* ulds = reinterpret_cast<float*>(lds_raw);  // [32][256] f32 (after) = 32KB

    const int tid = threadIdx.x;
    const int tile = ((blockIdx.x & 7) << 8) + (blockIdx.x >> 3);  // XCD swizzle
    const int t0 = tile << 8;

    const int lane = tid & 63;
    const int w = tid >> 6;
    const int n16 = lane & 15, g4 = lane >> 4;
    const int boff = 16 * n16 + 8 * g4;

    // staging role: plane pl = tid>>3, 4 m's (8B) per thread per granule.
    const int pl = tid >> 3, sub = tid & 7;
    const f16* gsrc = S16 + (long)pl * SPITCH + MOFF;
    f16* ring_pl = ring + (pl << 9);

    #pragma unroll 1
    for (int j = 0; j <= 10; ++j) {                    // prologue: granules 0..10
        const int m0 = t0 + 752 - 32 * j + 4 * sub;
        const uint2 v = *reinterpret_cast<const uint2*>(gsrc + m0);
        *reinterpret_cast<uint2*>(ring_pl + (m0 & 511)) = v;
    }
    __syncthreads();

    f32x4 acc[4][2] = {};

    f16x8 aA[4], aB[4];
    #pragma unroll
    for (int b = 0; b < 4; ++b)
        aA[b] = *reinterpret_cast<const f16x8*>(
            AF + ((long)((4 * w + b) * NSTEP + 0) * 64 + lane) * 8);

    // ping-pong u-loop: 32 steps in pairs + tail, no frag copies
    #pragma unroll 1
    for (int u = 0; u < 32; u += 2) {
        mstep(u,     t0, tid, w, lane, boff, gsrc, ring_pl, ring, AF, aA, aB, acc, true);
        mstep(u + 1, t0, tid, w, lane, boff, gsrc, ring_pl, ring, AF, aB, aA, acc, true);
    }
    mstep(32, t0, tid, w, lane, boff, gsrc, ring_pl, ring, AF, aA, aB, acc, false);

    // ---- write u to LDS (ring dead; last mstep barrier protects reuse)
    #pragma unroll
    for (int b = 0; b < 4; ++b) {
        const int i = 4 * w + b;
        #pragma unroll
        for (int e = 0; e < 2; ++e)
            #pragma unroll
            for (int j = 0; j < 4; ++j)
                ulds[(2 * i + e) * 256 + (16 * n16 + 4 * g4 + j)] = acc[b][e][j];
    }
    __syncthreads();

    // ---- per-thread 16-pt inverse DFT (real part) + store
    float ur[16], ui[16];
    #pragma unroll
    for (int i = 0; i < 16; ++i) {
        ur[i] = ulds[(2 * i + 0) * 256 + tid];
        ui[i] = ulds[(2 * i + 1) * 256 + tid];
    }
    const int t = t0 + tid;
    #pragma unroll
    for (int c = 0; c < 16; ++c) {
        float o = 0.f;
        #pragma unroll
        for (int i = 0; i < 16; ++i) {
            const int k = (i * c) & 15;
            o = fmaf(COS16[k], ur[i], fmaf(-SIN16[k], ui[i], o));
        }
        if (t < T_OUT) out[(long)c * T_OUT + t] = o;
    }
}

extern "C" void kernel_launch(void* const* d_in, const int* in_sizes, int n_in,
                              void* d_out, int out_size, void* d_ws, size_t ws_size,
                              hipStream_t stream)
{
    const float* sre   = (const float*)d_in[0];
    const float* sim   = (const float*)d_in[1];
    const float* coeff = (const float*)d_in[2];
    float* out = (float*)d_out;

    f16* S16 = (f16*)d_ws;                         // 32 * 525376 * 2B = 33.62 MB
    f16* AF  = S16 + (long)NPLANES * SPITCH;       // 16*33*512 f16 = 540 KB

    prep_sig<<<dim3(2053), dim3(256), 0, stream>>>(sre, sim, S16);
    prep_afrag<<<dim3((16 * NSTEP * 64 + 255) / 256), dim3(256), 0, stream>>>(coeff, AF);
    // 2048 tiles x 256 t; LDS = 32768 B -> 5 blocks/CU
    wdm_mfma<<<dim3(2048), dim3(256), 32768, stream>>>(S16, AF, out);
}

// Round 10
// 84.536 us; speedup vs baseline: 13.9799x; 1.0902x over previous
//
#include <hip/hip_runtime.h>

#define T_OUT    524287
#define SIG_LEN  8388608
#define SPITCH   525376            // f16 per plane: m in [-544, 524832)
#define MOFF     544
#define NPLANES  32                // 16 phases x (re, im)
#define NST      66                // K=16 steps: d = 16u-16+p-kappa covers [0,1024)
#define RF16     1280              // ring f16 per plane
#define RUNITS   160               // 16B units per plane
#define PLB      2560              // plane pitch bytes (ring & epilogue views)

typedef _Float16 f16;
typedef _Float16 f16x8 __attribute__((ext_vector_type(8)));
typedef float    f32x16 __attribute__((ext_vector_type(16)));

// ============ prep 1: phase-split signal to f16 planes (R9-verified) ============
__global__ __launch_bounds__(256)
void prep_sig(const float* __restrict__ sre,
              const float* __restrict__ sim,
              f16* __restrict__ S16)
{
    __shared__ f16 lf[2 * 4104];
    const int tid = threadIdx.x;
    const int M0 = -544 + 256 * (int)blockIdx.x;
    const long N0 = 16L * M0 - 16;

    #pragma unroll
    for (int c = 0; c < 8; ++c) {
        const int e = c >> 2, cc = c & 3;
        const int k = 4 * (tid + 256 * cc);
        const long n = N0 + k;
        const float* src = e ? sim : sre;
        float4 v = make_float4(0.f, 0.f, 0.f, 0.f);
        if (n >= 0 && n + 4 <= SIG_LEN) {
            v = *reinterpret_cast<const float4*>(src + n);
        } else {
            if (n     >= 0 && n     < SIG_LEN) v.x = src[n];
            if (n + 1 >= 0 && n + 1 < SIG_LEN) v.y = src[n + 1];
            if (n + 2 >= 0 && n + 2 < SIG_LEN) v.z = src[n + 2];
            if (n + 3 >= 0 && n + 3 < SIG_LEN) v.w = src[n + 3];
        }
        f16 h[4] = {(f16)v.x, (f16)v.y, (f16)v.z, (f16)v.w};
        *reinterpret_cast<uint2*>(&lf[e * 4104 + k]) = *reinterpret_cast<const uint2*>(h);
    }
    if (tid < 2) {
        const long n = N0 + 4096;
        const float x = (n >= 0 && n < SIG_LEN) ? (tid ? sim[n] : sre[n]) : 0.f;
        lf[tid * 4104 + 4096] = (f16)x;
    }
    __syncthreads();

    const int pl = tid & 31, i = pl >> 1, e = pl & 1;
    #pragma unroll
    for (int q = 0; q < 4; ++q) {
        const int a = (tid >> 5) + 8 * q;
        const int mr = M0 + 8 * a;
        if (mr + 8 <= 524832) {
            f16 h[8];
            #pragma unroll
            for (int j = 0; j < 8; ++j)
                h[j] = lf[e * 4104 + 128 * a + 16 * j + 16 - i];
            *reinterpret_cast<uint4*>(S16 + (long)pl * SPITCH + (MOFF + mr)) =
                *reinterpret_cast<const uint4*>(h);
        }
    }
}

// ============ prep 2: per-lane A fragments for 32x32x16 ============
// AF[((i*NST+u)*64+lane)*8+e] = Hpad[16u-16 + (lane&31) - (8*(lane>>5)+e)],
// Hpad[d] = coeff[16d+i] for d in [0,1024), else 0.
__global__ void prep_afrag(const float* __restrict__ coeff, f16* __restrict__ AF)
{
    const int gid = blockIdx.x * 256 + threadIdx.x;
    if (gid >= 16 * NST * 64) return;
    const int lane = gid & 63;
    const int fi = gid >> 6;
    const int i = fi / NST, u = fi % NST;
    const int p = lane & 31, g = lane >> 5;
    f16 v[8];
    #pragma unroll
    for (int e = 0; e < 8; ++e) {
        const int d = 16 * u - 16 + p - (8 * g + e);
        v[e] = (d >= 0 && d < 1024) ? (f16)coeff[16 * d + i] : (f16)0.f;
    }
    *reinterpret_cast<f16x8*>(AF + (long)gid * 8) = *reinterpret_cast<const f16x8*>(v);
}

// twiddles cos/sin(2*pi*k/16)
#define TC1 0.9238795325112867f
#define TC2 0.7071067811865476f
#define TC3 0.3826834323650898f
__device__ __constant__ const float COS16[16] = { 1.f,  TC1,  TC2,  TC3, 0.f, -TC3, -TC2, -TC1,
                                                 -1.f, -TC1, -TC2, -TC3, 0.f,  TC3,  TC2,  TC1};
__device__ __constant__ const float SIN16[16] = { 0.f,  TC3,  TC2,  TC1, 1.f,  TC1,  TC2,  TC3,
                                                  0.f, -TC3, -TC2, -TC1,-1.f, -TC1, -TC2, -TC3};

__device__ __forceinline__ int phi(int vu) { return vu ^ ((vu >> 2) & 7); }  // ring unit swizzle
__device__ __forceinline__ int psi(int uu) { return uu ^ ((uu >> 3) & 7); }  // epilogue unit swizzle

// ============ main: 32x32x16 MFMA polyphase FIR + 16-pt real inverse DFT ============
__global__ __launch_bounds__(256, 2)
void wdm_mfma(const f16* __restrict__ S16, const f16* __restrict__ AF,
              float* __restrict__ out)
{
    extern __shared__ char lds_raw[];
    const int tid  = threadIdx.x;
    const int lane = tid & 63, w = tid >> 6;
    const int n = lane & 31, g = lane >> 5;
    const int tile = ((blockIdx.x & 7) << 6) + (blockIdx.x >> 3);   // XCD swizzle, 512=8*64
    const int t0 = tile << 10;                                      // 1024 t per block

    // staging role: plane spl, 8 threads per plane
    const int spl = tid >> 3, ss = tid & 7;
    const f16* gsrc = S16 + (long)spl * SPITCH + MOFF;
    char* ringpl = lds_raw + spl * PLB;

    // prologue: stage m in [t0+416, t0+1567] (144 units/plane, 18/thread)
    #pragma unroll 1
    for (int jj = 0; jj < 18; ++jj) {
        const int m0 = t0 + 416 + 8 * (ss + 8 * jj);
        const uint4 v = *reinterpret_cast<const uint4*>(gsrc + m0);
        const int vu = (int)((unsigned)m0 % RF16) >> 3;
        *reinterpret_cast<uint4*>(ringpl + phi(vu) * 16) = v;
    }

    // A fragments: ping-pong, prefetch distance 2
    const f16x8* AFW = reinterpret_cast<const f16x8*>(AF) + ((long)(4 * w) * NST) * 64 + lane;
    f16x8 aA[4], aB[4];
    #pragma unroll
    for (int b = 0; b < 4; ++b) {
        aA[b] = AFW[(long)b * NST * 64];
        aB[b] = AFW[(long)b * NST * 64 + 64];
    }

    f32x16 acc[4][2];
    #pragma unroll
    for (int b = 0; b < 4; ++b)
        #pragma unroll
        for (int e = 0; e < 2; ++e)
            #pragma unroll
            for (int x = 0; x < 16; ++x) acc[b][e][x] = 0.f;

    __syncthreads();

    // B read-unit tracker: m(u) = t0 + 528 - 16u + 32n + 8g, unit = (m mod 1280)>>3
    int ru = (int)((unsigned)(t0 + 528 + 32 * n + 8 * g) % RF16) >> 3;
    const char* rbase = lds_raw + (w << 3) * PLB;   // wave-w plane group base

    auto STEP = [&](int u, f16x8 (&cur)[4], bool pf) {
        const int byt = phi(ru) << 4;
        #pragma unroll
        for (int b = 0; b < 4; ++b) {
            const f16x8 bre = *reinterpret_cast<const f16x8*>(rbase + (2 * b + 0) * PLB + byt);
            const f16x8 bim = *reinterpret_cast<const f16x8*>(rbase + (2 * b + 1) * PLB + byt);
            acc[b][0] = __builtin_amdgcn_mfma_f32_32x32x16_f16(cur[b], bre, acc[b][0], 0, 0, 0);
            acc[b][1] = __builtin_amdgcn_mfma_f32_32x32x16_f16(cur[b], bim, acc[b][1], 0, 0, 0);
        }
        if (pf) {
            #pragma unroll
            for (int b = 0; b < 4; ++b)
                cur[b] = AFW[(long)b * NST * 64 + (long)(u + 2) * 64];
        }
        ru -= 2; if (ru < 0) ru += RUNITS;
    };

    // 8 stage blocks x 8 steps; T14: loads issued at block start, ds_write + barrier at end
    #pragma unroll 1
    for (int k = 0; k < 8; ++k) {
        const int mb = t0 + 288 - 128 * k + 8 * ss;
        const int mc0 = (mb      < -544) ? -544 : mb;        // clamp: OOB source, slots never read
        const int mc1 = (mb + 64 < -544) ? -544 : (mb + 64);
        const uint4 sv0 = *reinterpret_cast<const uint4*>(gsrc + mc0);
        const uint4 sv1 = *reinterpret_cast<const uint4*>(gsrc + mc1);
        STEP(8 * k + 0, aA, true);  STEP(8 * k + 1, aB, true);
        STEP(8 * k + 2, aA, true);  STEP(8 * k + 3, aB, true);
        STEP(8 * k + 4, aA, true);  STEP(8 * k + 5, aB, true);
        STEP(8 * k + 6, aA, true);  STEP(8 * k + 7, aB, true);
        const int vu0 = (int)((unsigned)(mb + 5120) % RF16) >> 3;
        const int vu1 = (int)((unsigned)(mb + 64 + 5120) % RF16) >> 3;
        *reinterpret_cast<uint4*>(ringpl + phi(vu0) * 16) = sv0;
        *reinterpret_cast<uint4*>(ringpl + phi(vu1) * 16) = sv1;
        __syncthreads();
    }
    STEP(64, aA, false);
    STEP(65, aB, false);

    // ---- epilogue: two 512-t halves through psi-swizzled LDS transpose ----
    __syncthreads();                                   // all ring reads done
    float* uf = reinterpret_cast<float*>(lds_raw);     // [32][640] f32 view (psi units)
    const int np = n & 15;
    #pragma unroll 1
    for (int h = 0; h < 2; ++h) {
        if ((n >> 4) == h) {
            #pragma unroll
            for (int b = 0; b < 4; ++b)
                #pragma unroll
                for (int e = 0; e < 2; ++e) {
                    float* up = uf + ((w << 3) + 2 * b + e) * 640;
                    #pragma unroll
                    for (int j = 0; j < 4; ++j) {
                        const int uu = 8 * np + g + 2 * j;   // t_local = 32np+4g+8j+{0..3}
                        float4 val;
                        val.x = acc[b][e][4 * j + 0]; val.y = acc[b][e][4 * j + 1];
                        val.z = acc[b][e][4 * j + 2]; val.w = acc[b][e][4 * j + 3];
                        *reinterpret_cast<float4*>(up + psi(uu) * 4) = val;
                    }
                }
        }
        __syncthreads();
        #pragma unroll
        for (int z = 0; z < 2; ++z) {
            const int tl = tid + 256 * z;
            const int foff = psi(tl >> 2) * 4 + (tl & 3);
            float ur[16], ui[16];
            #pragma unroll
            for (int i = 0; i < 16; ++i) {
                ur[i] = uf[(2 * i + 0) * 640 + foff];
                ui[i] = uf[(2 * i + 1) * 640 + foff];
            }
            const int t = t0 + 512 * h + tl;
            #pragma unroll
            for (int c = 0; c < 16; ++c) {
                float o = 0.f;
                #pragma unroll
                for (int i = 0; i < 16; ++i) {
                    const int kk = (i * c) & 15;
                    o = fmaf(COS16[kk], ur[i], fmaf(-SIN16[kk], ui[i], o));
                }
                if (t < T_OUT) out[(long)c * T_OUT + t] = o;
            }
        }
        if (h == 0) __syncthreads();
    }
}

extern "C" void kernel_launch(void* const* d_in, const int* in_sizes, int n_in,
                              void* d_out, int out_size, void* d_ws, size_t ws_size,
                              hipStream_t stream)
{
    const float* sre   = (const float*)d_in[0];
    const float* sim   = (const float*)d_in[1];
    const float* coeff = (const float*)d_in[2];
    float* out = (float*)d_out;

    f16* S16 = (f16*)d_ws;                         // 32 * 525376 * 2B = 33.62 MB
    f16* AF  = S16 + (long)NPLANES * SPITCH;       // 16*66*64*8 f16 = 1.03 MB

    prep_sig<<<dim3(2053), dim3(256), 0, stream>>>(sre, sim, S16);
    prep_afrag<<<dim3((16 * NST * 64 + 255) / 256), dim3(256), 0, stream>>>(coeff, AF);
    // 512 tiles x 1024 t; LDS = 32 planes * 2560 B = 81920 B -> 2 blocks/CU
    wdm_mfma<<<dim3(512), dim3(256), NPLANES * PLB, stream>>>(S16, AF, out);
}

// Round 11
// 75.001 us; speedup vs baseline: 15.7573x; 1.1271x over previous
//
#include <hip/hip_runtime.h>

#define T_OUT    524287
#define SIG_LEN  8388608
#define SPITCH   525376            // f16 per plane: m in [-544, 524832)
#define MOFF     544
#define NPLANES  32                // 16 phases x (re, im)
#define NST      66                // K=16 steps: d = 16u-16+p-kappa covers [0,1024)
#define RF16     1280              // ring f16 per plane
#define RUNITS   160               // 16B units per plane
#define PLB      2560              // plane pitch bytes (ring & epilogue views)

typedef _Float16 f16;
typedef _Float16 f16x8 __attribute__((ext_vector_type(8)));
typedef float    f32x16 __attribute__((ext_vector_type(16)));

// ============ prep 1: phase-split signal to f16 planes (R9-verified) ============
__global__ __launch_bounds__(256)
void prep_sig(const float* __restrict__ sre,
              const float* __restrict__ sim,
              f16* __restrict__ S16)
{
    __shared__ f16 lf[2 * 4104];
    const int tid = threadIdx.x;
    const int M0 = -544 + 256 * (int)blockIdx.x;
    const long N0 = 16L * M0 - 16;

    #pragma unroll
    for (int c = 0; c < 8; ++c) {
        const int e = c >> 2, cc = c & 3;
        const int k = 4 * (tid + 256 * cc);
        const long n = N0 + k;
        const float* src = e ? sim : sre;
        float4 v = make_float4(0.f, 0.f, 0.f, 0.f);
        if (n >= 0 && n + 4 <= SIG_LEN) {
            v = *reinterpret_cast<const float4*>(src + n);
        } else {
            if (n     >= 0 && n     < SIG_LEN) v.x = src[n];
            if (n + 1 >= 0 && n + 1 < SIG_LEN) v.y = src[n + 1];
            if (n + 2 >= 0 && n + 2 < SIG_LEN) v.z = src[n + 2];
            if (n + 3 >= 0 && n + 3 < SIG_LEN) v.w = src[n + 3];
        }
        f16 h[4] = {(f16)v.x, (f16)v.y, (f16)v.z, (f16)v.w};
        *reinterpret_cast<uint2*>(&lf[e * 4104 + k]) = *reinterpret_cast<const uint2*>(h);
    }
    if (tid < 2) {
        const long n = N0 + 4096;
        const float x = (n >= 0 && n < SIG_LEN) ? (tid ? sim[n] : sre[n]) : 0.f;
        lf[tid * 4104 + 4096] = (f16)x;
    }
    __syncthreads();

    const int pl = tid & 31, i = pl >> 1, e = pl & 1;
    #pragma unroll
    for (int q = 0; q < 4; ++q) {
        const int a = (tid >> 5) + 8 * q;
        const int mr = M0 + 8 * a;
        if (mr + 8 <= 524832) {
            f16 h[8];
            #pragma unroll
            for (int j = 0; j < 8; ++j)
                h[j] = lf[e * 4104 + 128 * a + 16 * j + 16 - i];
            *reinterpret_cast<uint4*>(S16 + (long)pl * SPITCH + (MOFF + mr)) =
                *reinterpret_cast<const uint4*>(h);
        }
    }
}

// ============ prep 2: per-lane A fragments for 32x32x16 (R10-verified) ============
__global__ void prep_afrag(const float* __restrict__ coeff, f16* __restrict__ AF)
{
    const int gid = blockIdx.x * 256 + threadIdx.x;
    if (gid >= 16 * NST * 64) return;
    const int lane = gid & 63;
    const int fi = gid >> 6;
    const int i = fi / NST, u = fi % NST;
    const int p = lane & 31, g = lane >> 5;
    f16 v[8];
    #pragma unroll
    for (int e = 0; e < 8; ++e) {
        const int d = 16 * u - 16 + p - (8 * g + e);
        v[e] = (d >= 0 && d < 1024) ? (f16)coeff[16 * d + i] : (f16)0.f;
    }
    *reinterpret_cast<f16x8*>(AF + (long)gid * 8) = *reinterpret_cast<const f16x8*>(v);
}

// twiddles cos/sin(2*pi*k/16)
#define TC1 0.9238795325112867f
#define TC2 0.7071067811865476f
#define TC3 0.3826834323650898f
__device__ __constant__ const float COS16[16] = { 1.f,  TC1,  TC2,  TC3, 0.f, -TC3, -TC2, -TC1,
                                                 -1.f, -TC1, -TC2, -TC3, 0.f,  TC3,  TC2,  TC1};
__device__ __constant__ const float SIN16[16] = { 0.f,  TC3,  TC2,  TC1, 1.f,  TC1,  TC2,  TC3,
                                                  0.f, -TC3, -TC2, -TC1,-1.f, -TC1, -TC2, -TC3};

__device__ __forceinline__ int phi(int vu) { return vu ^ ((vu >> 2) & 7); }  // ring unit swizzle
__device__ __forceinline__ int psi(int uu) { return uu ^ ((uu >> 3) & 7); }  // epilogue unit swizzle

// ============ main: 32x32x16 MFMA, 8 waves (2 branches/wave), 4 waves/SIMD ============
__global__ __launch_bounds__(512, 4)
void wdm_mfma(const f16* __restrict__ S16, const f16* __restrict__ AF,
              float* __restrict__ out)
{
    extern __shared__ char lds_raw[];
    const int tid  = threadIdx.x;
    const int lane = tid & 63, w = tid >> 6;                        // 8 waves
    const int n = lane & 31, g = lane >> 5;
    const int tile = ((blockIdx.x & 7) << 6) + (blockIdx.x >> 3);   // XCD swizzle
    const int t0 = tile << 10;                                      // 1024 t per block

    // staging role: plane spl (32 planes x 16 threads), 1 unit/thread/k-block
    const int spl = tid >> 4, ss = tid & 15;
    const f16* gsrc = S16 + (long)spl * SPITCH + MOFF;
    char* ringpl = lds_raw + spl * PLB;
    const int sx = spl & 7;                                         // write-col XOR

    // prologue: stage m in [t0+416, t0+1567] (144 units/plane, 9/thread)
    #pragma unroll
    for (int jj = 0; jj < 9; ++jj) {
        const int m0 = t0 + 416 + 8 * (ss + 16 * jj);
        const uint4 v = *reinterpret_cast<const uint4*>(gsrc + m0);
        const int vu = (int)((unsigned)m0 % RF16) >> 3;
        *reinterpret_cast<uint4*>(ringpl + ((phi(vu) ^ sx) << 4)) = v;
    }

    // A fragments: branches 2w, 2w+1; ping-pong, prefetch distance 2
    const f16x8* AFW = reinterpret_cast<const f16x8*>(AF) + ((long)(2 * w) * NST) * 64 + lane;
    f16x8 aA[2], aB[2];
    #pragma unroll
    for (int b = 0; b < 2; ++b) {
        aA[b] = AFW[(long)b * NST * 64];
        aB[b] = AFW[(long)b * NST * 64 + 64];
    }

    f32x16 acc[2][2];
    #pragma unroll
    for (int b = 0; b < 2; ++b)
        #pragma unroll
        for (int e = 0; e < 2; ++e)
            #pragma unroll
            for (int x = 0; x < 16; ++x) acc[b][e][x] = 0.f;

    __syncthreads();

    // B read-unit tracker: m(u) = t0 + 528 - 16u + 32n + 8g
    int ru = (int)((unsigned)(t0 + 528 + 32 * n + 8 * g) % RF16) >> 3;
    const char* rbase = lds_raw + (w << 2) * PLB;   // plane 4w
    const int rx0 = (4 * w) & 7;                    // read-col XOR base

    auto STEP = [&](int u, f16x8 (&cur)[2], bool pf) {
        const int pr = phi(ru);
        #pragma unroll
        for (int b = 0; b < 2; ++b) {
            #pragma unroll
            for (int e = 0; e < 2; ++e) {
                const int pe = 2 * b + e;
                const f16x8 bv = *reinterpret_cast<const f16x8*>(
                    rbase + pe * PLB + ((pr ^ (rx0 + pe)) << 4));
                acc[b][e] = __builtin_amdgcn_mfma_f32_32x32x16_f16(cur[b], bv, acc[b][e], 0, 0, 0);
            }
        }
        if (pf) {
            #pragma unroll
            for (int b = 0; b < 2; ++b)
                cur[b] = AFW[(long)b * NST * 64 + (long)(u + 2) * 64];
        }
        ru -= 2; if (ru < 0) ru += RUNITS;
    };

    // 8 stage blocks x 8 steps; T14: load at block start, ds_write + barrier at end
    #pragma unroll 1
    for (int k = 0; k < 8; ++k) {
        const int mb = t0 + 288 - 128 * k + 8 * ss;
        const int mc = (mb < -544) ? -544 : mb;      // OOB slots never read
        const uint4 sv = *reinterpret_cast<const uint4*>(gsrc + mc);
        STEP(8 * k + 0, aA, true);  STEP(8 * k + 1, aB, true);
        STEP(8 * k + 2, aA, true);  STEP(8 * k + 3, aB, true);
        STEP(8 * k + 4, aA, true);  STEP(8 * k + 5, aB, true);
        STEP(8 * k + 6, aA, true);  STEP(8 * k + 7, aB, true);
        const int vu = (int)((unsigned)(mb + 5120) % RF16) >> 3;
        *reinterpret_cast<uint4*>(ringpl + ((phi(vu) ^ sx) << 4)) = sv;
        __syncthreads();
    }
    STEP(64, aA, false);
    STEP(65, aB, false);

    // ---- epilogue: two 512-t halves through psi-swizzled LDS transpose ----
    __syncthreads();                                   // all ring reads done
    float* uf = reinterpret_cast<float*>(lds_raw);     // [32][640] f32 view
    const int np = n & 15;
    #pragma unroll 1
    for (int h = 0; h < 2; ++h) {
        if ((n >> 4) == h) {
            #pragma unroll
            for (int b = 0; b < 2; ++b)
                #pragma unroll
                for (int e = 0; e < 2; ++e) {
                    float* up = uf + ((w << 2) + 2 * b + e) * 640;
                    #pragma unroll
                    for (int j = 0; j < 4; ++j) {
                        const int uu = 8 * np + g + 2 * j;   // t_local = 4*uu + c
                        float4 val;
                        val.x = acc[b][e][4 * j + 0]; val.y = acc[b][e][4 * j + 1];
                        val.z = acc[b][e][4 * j + 2]; val.w = acc[b][e][4 * j + 3];
                        *reinterpret_cast<float4*>(up + psi(uu) * 4) = val;
                    }
                }
        }
        __syncthreads();
        {
            const int tl = tid;                         // 512 t per half, 1/thread
            const int foff = psi(tl >> 2) * 4 + (tl & 3);
            float ur[16], ui[16];
            #pragma unroll
            for (int i = 0; i < 16; ++i) {
                ur[i] = uf[(2 * i + 0) * 640 + foff];
                ui[i] = uf[(2 * i + 1) * 640 + foff];
            }
            const int t = t0 + 512 * h + tl;
            #pragma unroll
            for (int c = 0; c < 16; ++c) {
                float o = 0.f;
                #pragma unroll
                for (int i = 0; i < 16; ++i) {
                    const int kk = (i * c) & 15;
                    o = fmaf(COS16[kk], ur[i], fmaf(-SIN16[kk], ui[i], o));
                }
                if (t < T_OUT) out[(long)c * T_OUT + t] = o;
            }
        }
        if (h == 0) __syncthreads();
    }
}

extern "C" void kernel_launch(void* const* d_in, const int* in_sizes, int n_in,
                              void* d_out, int out_size, void* d_ws, size_t ws_size,
                              hipStream_t stream)
{
    const float* sre   = (const float*)d_in[0];
    const float* sim   = (const float*)d_in[1];
    const float* coeff = (const float*)d_in[2];
    float* out = (float*)d_out;

    f16* S16 = (f16*)d_ws;                         // 32 * 525376 * 2B = 33.62 MB
    f16* AF  = S16 + (long)NPLANES * SPITCH;       // 16*66*64*8 f16 = 1.03 MB

    prep_sig<<<dim3(2053), dim3(256), 0, stream>>>(sre, sim, S16);
    prep_afrag<<<dim3((16 * NST * 64 + 255) / 256), dim3(256), 0, stream>>>(coeff, AF);
    // 512 tiles x 1024 t; 512 threads (8 waves); LDS = 81920 B -> 2 blocks/CU
    wdm_mfma<<<dim3(512), dim3(512), NPLANES * PLB, stream>>>(S16, AF, out);
}

// Round 12
// 71.562 us; speedup vs baseline: 16.5144x; 1.0480x over previous
//
#include <hip/hip_runtime.h>

#define T_OUT    524287
#define SIG_LEN  8388608
#define SPITCH   525376            // f16 per plane: m in [-544, 524832)
#define MOFF     544
#define NPLANES  32                // 16 phases x (re, im)
#define NST      66                // K=16 steps: d = 16u-16+p-kappa covers [0,1024)
#define RF16     1280              // ring f16 per plane (min safe: slot-reuse >= 1263)
#define RUNITS   160               // 16B units per plane
#define PLB      2560              // plane pitch bytes (ring & epilogue views)
#define NSIGBLK  2053              // prep: signal blocks, then afrag blocks

typedef _Float16 f16;
typedef _Float16 f16x8 __attribute__((ext_vector_type(8)));
typedef float    f32x16 __attribute__((ext_vector_type(16)));

// twiddles cos/sin(2*pi*k/16) — constexpr so compile-time indices fold to literals
#define TC1 0.9238795325112867f
#define TC2 0.7071067811865476f
#define TC3 0.3826834323650898f
constexpr float COS16[16] = { 1.f,  TC1,  TC2,  TC3, 0.f, -TC3, -TC2, -TC1,
                             -1.f, -TC1, -TC2, -TC3, 0.f,  TC3,  TC2,  TC1};
constexpr float SIN16[16] = { 0.f,  TC3,  TC2,  TC1, 1.f,  TC1,  TC2,  TC3,
                              0.f, -TC3, -TC2, -TC1,-1.f, -TC1, -TC2, -TC3};

__device__ __forceinline__ int phi(int vu) { return vu ^ ((vu >> 2) & 7); }  // ring unit swizzle
__device__ __forceinline__ int psi(int uu) { return uu ^ ((uu >> 3) & 7); }  // epilogue unit swizzle

// ============ merged prep: blocks [0,2053) = phase-split; [2053,2317) = A-frags ============
__global__ __launch_bounds__(256)
void prep_all(const float* __restrict__ sre, const float* __restrict__ sim,
              const float* __restrict__ coeff,
              f16* __restrict__ S16, f16* __restrict__ AF)
{
    __shared__ f16 lf[2 * 4104];
    const int tid = threadIdx.x;
    const int bid = blockIdx.x;

    if (bid >= NSIGBLK) {
        // ---- A-fragments for 32x32x16 (R10-verified) ----
        const int gid = (bid - NSIGBLK) * 256 + tid;
        if (gid >= 16 * NST * 64) return;
        const int lane = gid & 63;
        const int fi = gid >> 6;
        const int i = fi / NST, u = fi % NST;
        const int p = lane & 31, g = lane >> 5;
        f16 v[8];
        #pragma unroll
        for (int e = 0; e < 8; ++e) {
            const int d = 16 * u - 16 + p - (8 * g + e);
            v[e] = (d >= 0 && d < 1024) ? (f16)coeff[16 * d + i] : (f16)0.f;
        }
        *reinterpret_cast<f16x8*>(AF + (long)gid * 8) = *reinterpret_cast<const f16x8*>(v);
        return;
    }

    // ---- phase-split signal to f16 planes (R9-verified) ----
    const int M0 = -544 + 256 * bid;
    const long N0 = 16L * M0 - 16;

    #pragma unroll
    for (int c = 0; c < 8; ++c) {
        const int e = c >> 2, cc = c & 3;
        const int k = 4 * (tid + 256 * cc);
        const long n = N0 + k;
        const float* src = e ? sim : sre;
        float4 v = make_float4(0.f, 0.f, 0.f, 0.f);
        if (n >= 0 && n + 4 <= SIG_LEN) {
            v = *reinterpret_cast<const float4*>(src + n);
        } else {
            if (n     >= 0 && n     < SIG_LEN) v.x = src[n];
            if (n + 1 >= 0 && n + 1 < SIG_LEN) v.y = src[n + 1];
            if (n + 2 >= 0 && n + 2 < SIG_LEN) v.z = src[n + 2];
            if (n + 3 >= 0 && n + 3 < SIG_LEN) v.w = src[n + 3];
        }
        f16 h[4] = {(f16)v.x, (f16)v.y, (f16)v.z, (f16)v.w};
        *reinterpret_cast<uint2*>(&lf[e * 4104 + k]) = *reinterpret_cast<const uint2*>(h);
    }
    if (tid < 2) {
        const long n = N0 + 4096;
        const float x = (n >= 0 && n < SIG_LEN) ? (tid ? sim[n] : sre[n]) : 0.f;
        lf[tid * 4104 + 4096] = (f16)x;
    }
    __syncthreads();

    const int pl = tid & 31, i = pl >> 1, e = pl & 1;
    #pragma unroll
    for (int q = 0; q < 4; ++q) {
        const int a = (tid >> 5) + 8 * q;
        const int mr = M0 + 8 * a;
        if (mr + 8 <= 524832) {
            f16 h[8];
            #pragma unroll
            for (int j = 0; j < 8; ++j)
                h[j] = lf[e * 4104 + 128 * a + 16 * j + 16 - i];
            *reinterpret_cast<uint4*>(S16 + (long)pl * SPITCH + (MOFF + mr)) =
                *reinterpret_cast<const uint4*>(h);
        }
    }
}

// ============ main: 32x32x16 MFMA, 8 waves (2 branches/wave), 4 waves/SIMD ============
__global__ __launch_bounds__(512, 4)
void wdm_mfma(const f16* __restrict__ S16, const f16* __restrict__ AF,
              float* __restrict__ out)
{
    extern __shared__ char lds_raw[];
    const int tid  = threadIdx.x;
    const int lane = tid & 63, w = tid >> 6;                        // 8 waves
    const int n = lane & 31, g = lane >> 5;
    const int tile = ((blockIdx.x & 7) << 6) + (blockIdx.x >> 3);   // XCD swizzle
    const int t0 = tile << 10;                                      // 1024 t per block

    // staging role: plane spl (32 planes x 16 threads), 1 unit/thread/k-block
    const int spl = tid >> 4, ss = tid & 15;
    const f16* gsrc = S16 + (long)spl * SPITCH + MOFF;
    char* ringpl = lds_raw + spl * PLB;
    const int sx = spl & 7;                                         // write-col XOR

    // prologue: stage m in [t0+416, t0+1567] (144 units/plane, 9/thread)
    #pragma unroll
    for (int jj = 0; jj < 9; ++jj) {
        const int m0 = t0 + 416 + 8 * (ss + 16 * jj);
        const uint4 v = *reinterpret_cast<const uint4*>(gsrc + m0);
        const int vu = (int)((unsigned)m0 % RF16) >> 3;
        *reinterpret_cast<uint4*>(ringpl + ((phi(vu) ^ sx) << 4)) = v;
    }

    // A fragments: branches 2w, 2w+1; ping-pong, prefetch distance 2
    const f16x8* AFW = reinterpret_cast<const f16x8*>(AF) + ((long)(2 * w) * NST) * 64 + lane;
    f16x8 aA[2], aB[2];
    #pragma unroll
    for (int b = 0; b < 2; ++b) {
        aA[b] = AFW[(long)b * NST * 64];
        aB[b] = AFW[(long)b * NST * 64 + 64];
    }

    f32x16 acc[2][2];
    #pragma unroll
    for (int b = 0; b < 2; ++b)
        #pragma unroll
        for (int e = 0; e < 2; ++e)
            #pragma unroll
            for (int x = 0; x < 16; ++x) acc[b][e][x] = 0.f;

    __syncthreads();

    // B read-unit tracker: m(u) = t0 + 528 - 16u + 32n + 8g
    int ru = (int)((unsigned)(t0 + 528 + 32 * n + 8 * g) % RF16) >> 3;
    const char* rbase = lds_raw + (w << 2) * PLB;   // plane 4w
    const int rx0 = (4 * w) & 7;                    // read-col XOR base

    auto STEP = [&](int u, f16x8 (&cur)[2], bool pf) {
        const int pr = phi(ru);
        f16x8 bv0 = *reinterpret_cast<const f16x8*>(rbase + 0 * PLB + ((pr ^ (rx0 + 0)) << 4));
        f16x8 bv1 = *reinterpret_cast<const f16x8*>(rbase + 1 * PLB + ((pr ^ (rx0 + 1)) << 4));
        f16x8 bv2 = *reinterpret_cast<const f16x8*>(rbase + 2 * PLB + ((pr ^ (rx0 + 2)) << 4));
        f16x8 bv3 = *reinterpret_cast<const f16x8*>(rbase + 3 * PLB + ((pr ^ (rx0 + 3)) << 4));
        __builtin_amdgcn_s_setprio(1);
        acc[0][0] = __builtin_amdgcn_mfma_f32_32x32x16_f16(cur[0], bv0, acc[0][0], 0, 0, 0);
        acc[0][1] = __builtin_amdgcn_mfma_f32_32x32x16_f16(cur[0], bv1, acc[0][1], 0, 0, 0);
        acc[1][0] = __builtin_amdgcn_mfma_f32_32x32x16_f16(cur[1], bv2, acc[1][0], 0, 0, 0);
        acc[1][1] = __builtin_amdgcn_mfma_f32_32x32x16_f16(cur[1], bv3, acc[1][1], 0, 0, 0);
        __builtin_amdgcn_s_setprio(0);
        if (pf) {
            #pragma unroll
            for (int b = 0; b < 2; ++b)
                cur[b] = AFW[(long)b * NST * 64 + (long)(u + 2) * 64];
        }
        ru -= 2; if (ru < 0) ru += RUNITS;
    };

    // 8 stage blocks x 8 steps; T14: load at block start, ds_write + barrier at end
    #pragma unroll 1
    for (int k = 0; k < 8; ++k) {
        const int mb = t0 + 288 - 128 * k + 8 * ss;
        const int mc = (mb < -544) ? -544 : mb;      // OOB slots never read
        const uint4 sv = *reinterpret_cast<const uint4*>(gsrc + mc);
        STEP(8 * k + 0, aA, true);  STEP(8 * k + 1, aB, true);
        STEP(8 * k + 2, aA, true);  STEP(8 * k + 3, aB, true);
        STEP(8 * k + 4, aA, true);  STEP(8 * k + 5, aB, true);
        STEP(8 * k + 6, aA, true);  STEP(8 * k + 7, aB, true);
        const int vu = (int)((unsigned)(mb + 5120) % RF16) >> 3;
        *reinterpret_cast<uint4*>(ringpl + ((phi(vu) ^ sx) << 4)) = sv;
        __syncthreads();
    }
    STEP(64, aA, false);
    STEP(65, aB, false);

    // ---- epilogue: two 512-t halves through psi-swizzled LDS transpose ----
    __syncthreads();                                   // all ring reads done
    float* uf = reinterpret_cast<float*>(lds_raw);     // [32][640] f32 view
    const int np = n & 15;
    #pragma unroll 1
    for (int h = 0; h < 2; ++h) {
        if ((n >> 4) == h) {
            #pragma unroll
            for (int b = 0; b < 2; ++b)
                #pragma unroll
                for (int e = 0; e < 2; ++e) {
                    float* up = uf + ((w << 2) + 2 * b + e) * 640;
                    #pragma unroll
                    for (int j = 0; j < 4; ++j) {
                        const int uu = 8 * np + g + 2 * j;   // t_local = 4*uu + c
                        float4 val;
                        val.x = acc[b][e][4 * j + 0]; val.y = acc[b][e][4 * j + 1];
                        val.z = acc[b][e][4 * j + 2]; val.w = acc[b][e][4 * j + 3];
                        *reinterpret_cast<float4*>(up + psi(uu) * 4) = val;
                    }
                }
        }
        __syncthreads();
        {
            const int tl = tid;                         // 512 t per half, 1/thread
            const int foff = psi(tl >> 2) * 4 + (tl & 3);
            float ur[16], ui[16];
            #pragma unroll
            for (int i = 0; i < 16; ++i) {
                ur[i] = uf[(2 * i + 0) * 640 + foff];
                ui[i] = uf[(2 * i + 1) * 640 + foff];
            }
            // symmetry-folded real-output 16-pt inverse DFT:
            // out[c] = E[c] - S[c], out[16-c] = E[c] + S[c]
            // E[c] = ur0 + (-1)^c ur8 + sum_{i=1..7} cos_ic (ur[i]+ur[16-i])
            // S[c] = sum_{i=1..7} sin_ic (ui[i]-ui[16-i])
            float P[7], M[7];
            #pragma unroll
            for (int i = 1; i <= 7; ++i) {
                P[i - 1] = ur[i] + ur[16 - i];
                M[i - 1] = ui[i] - ui[16 - i];
            }
            float o[16];
            #pragma unroll
            for (int c = 0; c <= 8; ++c) {
                float e = (c & 1) ? (ur[0] - ur[8]) : (ur[0] + ur[8]);
                #pragma unroll
                for (int i = 1; i <= 7; ++i)
                    e = fmaf(COS16[(i * c) & 15], P[i - 1], e);
                o[c] = e;
            }
            #pragma unroll
            for (int c = 1; c <= 7; ++c) {
                float s = 0.f;
                #pragma unroll
                for (int i = 1; i <= 7; ++i)
                    s = fmaf(SIN16[(i * c) & 15], M[i - 1], s);
                o[16 - c] = o[c] + s;
                o[c]      = o[c] - s;
            }
            const int t = t0 + 512 * h + tl;
            if (t < T_OUT) {
                #pragma unroll
                for (int c = 0; c < 16; ++c)
                    out[(long)c * T_OUT + t] = o[c];
            }
        }
        if (h == 0) __syncthreads();
    }
}

extern "C" void kernel_launch(void* const* d_in, const int* in_sizes, int n_in,
                              void* d_out, int out_size, void* d_ws, size_t ws_size,
                              hipStream_t stream)
{
    const float* sre   = (const float*)d_in[0];
    const float* sim   = (const float*)d_in[1];
    const float* coeff = (const float*)d_in[2];
    float* out = (float*)d_out;

    f16* S16 = (f16*)d_ws;                         // 32 * 525376 * 2B = 33.62 MB
    f16* AF  = S16 + (long)NPLANES * SPITCH;       // 16*66*64*8 f16 = 1.03 MB

    // merged prep: 2053 signal blocks + 264 afrag blocks (16*66*64/256)
    prep_all<<<dim3(NSIGBLK + 264), dim3(256), 0, stream>>>(sre, sim, coeff, S16, AF);
    // 512 tiles x 1024 t; 512 threads (8 waves); LDS = 81920 B -> 2 blocks/CU
    wdm_mfma<<<dim3(512), dim3(512), NPLANES * PLB, stream>>>(S16, AF, out);
}